// Round 18
// baseline (373.858 us; speedup 1.0000x reference)
//
#include <hip/hip_runtime.h>
#include <hip/hip_bf16.h>
#include <hip/hip_fp16.h>
#include <cstdint>
#include <cstddef>

typedef _Float16 h8 __attribute__((ext_vector_type(8)));
typedef float f4 __attribute__((ext_vector_type(4)));

#define CNT_PAD 16   // one counter per 64B line

// ---------------- CSR scans ----------------

__global__ __launch_bounds__(256) void k_scan_a(const int* __restrict__ cnt_pad, int* __restrict__ offs,
                                                int* __restrict__ partials, float* __restrict__ dinv, int N) {
    __shared__ int sh[256];
    int t = threadIdx.x;
    int i = blockIdx.x * 256 + t;
    int v = (i < N) ? (cnt_pad[(size_t)i * CNT_PAD] + 1) : 0;
    sh[t] = v;
    __syncthreads();
    for (int d = 1; d < 256; d <<= 1) {
        int add = (t >= d) ? sh[t - d] : 0;
        __syncthreads();
        sh[t] += add;
        __syncthreads();
    }
    if (i < N) {
        offs[i] = sh[t] - v;
        dinv[i] = rsqrtf((float)v);
    }
    if (t == 255) partials[blockIdx.x] = sh[255];
}

__global__ __launch_bounds__(512) void k_scan_b(int* __restrict__ partials, int nb) {
    __shared__ int sh[512];
    int t = threadIdx.x;
    int v = (t < nb) ? partials[t] : 0;
    sh[t] = v;
    __syncthreads();
    for (int d = 1; d < 512; d <<= 1) {
        int add = (t >= d) ? sh[t - d] : 0;
        __syncthreads();
        sh[t] += add;
        __syncthreads();
    }
    if (t < nb) partials[t] = sh[t];
}

// finalize offs; write self-loop record at offs[i]+cnt (== offs[i+1]-1)
__global__ __launch_bounds__(256) void k_scan_c(int* __restrict__ offs, const int* __restrict__ partials,
                                                const int* __restrict__ cnt_pad, const float* __restrict__ dinv,
                                                long long* __restrict__ cpack, int N, int nb) {
    int i = blockIdx.x * 256 + threadIdx.x;
    if (i < N) {
        int b = i >> 8;
        int o = offs[i] + (b > 0 ? partials[b - 1] : 0);
        offs[i] = o;
        int cnt = cnt_pad[(size_t)i * CNT_PAD];
        float di = dinv[i];
        unsigned int nrm = (unsigned int)__float_as_int(di * di);
        long long v = ((long long)nrm << 32) | (unsigned int)i;
        __builtin_nontemporal_store(v, &cpack[o + cnt]);
    } else if (i == N) {
        offs[N] = partials[nb - 1];
    }
}

// no atomic: pos = offs[dst] + rank; 1 edge per thread; NT scatter
__global__ __launch_bounds__(256) void k_fill2(const int* __restrict__ src, const int* __restrict__ dst,
                                               const int* __restrict__ rank, const int* __restrict__ offs,
                                               const float* __restrict__ dinv,
                                               long long* __restrict__ cpack, int E) {
    int i = blockIdx.x * 256 + threadIdx.x;
    if (i < E) {
        int s = src[i], d = dst[i];
        int pos = offs[d] + rank[i];
        unsigned int nrm = (unsigned int)__float_as_int(dinv[s] * dinv[d]);
        long long v = ((long long)nrm << 32) | (unsigned int)s;
        __builtin_nontemporal_store(v, &cpack[pos]);
    }
}

// ---------------- weight prep (once) ----------------
// WT[l][c][k] = W_l[k][c] fp16 (3x128x128); W2T[c][k] = w2[k][c] fp16 (64x64)

__global__ __launch_bounds__(256) void k_prep_w(const float* __restrict__ w0, const float* __restrict__ w1,
                                                const float* __restrict__ w2g, _Float16* __restrict__ WT) {
    int idx = blockIdx.x * 256 + threadIdx.x;
    if (idx < 3 * 16384) {
        int l = idx >> 14, rem = idx & 16383, c = rem >> 7, k = rem & 127;
        const float* W = (l == 0) ? w0 : (l == 1) ? w1 : w2g;
        WT[idx] = (_Float16)W[k * 128 + c];
    }
}

__global__ __launch_bounds__(256) void k_prep_w2(const float* __restrict__ w2, _Float16* __restrict__ W2T) {
    int idx = blockIdx.x * 256 + threadIdx.x;   // 4096 elems
    if (idx < 4096) {
        int c = idx >> 6, k = idx & 63;
        W2T[idx] = (_Float16)w2[k * 64 + c];
    }
}

// ---------------- merged: edge count+rank (blocks [0,ebCount)) ∥ feat+GEMM0 (rest) ----------------
// LDS slimmed to ~9.3 KB; w2^T read from global (L2-hot); h1 staged inside Fl cols 64..127.

__global__ __launch_bounds__(256) void k_count_feat(const int* __restrict__ edst, int* __restrict__ cnt_pad,
                                                    int* __restrict__ rank, int E, int ebCount,
                                                    const int* __restrict__ label, const float* __restrict__ bbox,
                                                    const float* __restrict__ emb,
                                                    const float* __restrict__ w1, const float* __restrict__ b1,
                                                    const float* __restrict__ b2,
                                                    const _Float16* __restrict__ W2Th,
                                                    const _Float16* __restrict__ WT0,
                                                    _Float16* __restrict__ G0, int N) {
    int t = threadIdx.x;

    if ((int)blockIdx.x < ebCount) {
        // ---- edge count + rank capture (no LDS touched) ----
        int i = blockIdx.x * 256 + t;
        if (i < E) rank[i] = atomicAdd(&cnt_pad[(size_t)edst[i] * CNT_PAD], 1);
        return;
    }

    // ---- feat + GEMM0 ----
    __shared__ float w1s[256];
    __shared__ float b1s[64], b2s[64];
    __shared__ _Float16 Fl[32][136];

    if (t < 256) w1s[t] = w1[t];
    if (t < 64) { b1s[t] = b1[t]; b2s[t] = b2[t]; }
    __syncthreads();   // FIX: w1s/b1s written by other waves — barrier before use
                       // (latent race since r11, masked by the old w2t staging loop)

    int wv = t >> 6, lane = t & 63;
    int r = lane & 15, q = lane >> 4;
    int blockBase = (blockIdx.x - ebCount) * 32;
    int nb0 = blockBase + wv * 8;

    // phase 1: ev -> Fl cols 0..63; h1 fp16 -> Fl cols 64..127
    #pragma unroll
    for (int nn = 0; nn < 8; ++nn) {
        int node = nb0 + nn;
        float h1 = 0.f;
        _Float16 ev = (_Float16)0.f;
        if (node < N) {
            float bb0 = bbox[node * 4 + 0];
            float bb1 = bbox[node * 4 + 1];
            float bb2 = bbox[node * 4 + 2];
            float bb3 = bbox[node * 4 + 3];
            h1 = fmaxf(bb0 * w1s[lane] + bb1 * w1s[64 + lane]
                     + bb2 * w1s[128 + lane] + bb3 * w1s[192 + lane] + b1s[lane], 0.f);
            ev = (_Float16)emb[(size_t)label[node] * 64 + lane];
        }
        Fl[wv * 8 + nn][lane] = ev;
        Fl[wv * 8 + nn][64 + lane] = (_Float16)h1;
    }
    __syncthreads();

    int rt = wv & 1, ch = wv >> 1;

    // phase 2a: read h1 A-frags, barrier, then overwrite cols 64..127 with h2
    h8 a0 = *(const h8*)&Fl[rt * 16 + r][64 + q * 8];
    h8 a1 = *(const h8*)&Fl[rt * 16 + r][96 + q * 8];
    __syncthreads();   // all h1 reads complete before any h2 write
    #pragma unroll
    for (int ct = 0; ct < 2; ++ct) {
        int col = ch * 32 + ct * 16 + r;
        h8 bv0 = *(const h8*)&W2Th[col * 64 + q * 8];
        h8 bv1 = *(const h8*)&W2Th[col * 64 + 32 + q * 8];
        f4 acc = {0.f, 0.f, 0.f, 0.f};
        acc = __builtin_amdgcn_mfma_f32_16x16x32_f16(a0, bv0, acc, 0, 0, 0);
        acc = __builtin_amdgcn_mfma_f32_16x16x32_f16(a1, bv1, acc, 0, 0, 0);
        float bb = b2s[col];
        #pragma unroll
        for (int i = 0; i < 4; ++i)
            Fl[rt * 16 + q * 4 + i][64 + col] = (_Float16)(acc[i] + bb);
    }
    __syncthreads();

    // phase 2b: G0 = Fl @ W0 (K=128)
    {
        h8 a[4];
        #pragma unroll
        for (int s = 0; s < 4; ++s) a[s] = *(const h8*)&Fl[rt * 16 + r][s * 32 + q * 8];
        #pragma unroll
        for (int ct = 0; ct < 4; ++ct) {
            int col = ch * 64 + ct * 16 + r;
            f4 acc = {0.f, 0.f, 0.f, 0.f};
            #pragma unroll
            for (int s = 0; s < 4; ++s) {
                h8 bv = *(const h8*)&WT0[(size_t)col * 128 + s * 32 + q * 8];
                acc = __builtin_amdgcn_mfma_f32_16x16x32_f16(a[s], bv, acc, 0, 0, 0);
            }
            #pragma unroll
            for (int i = 0; i < 4; ++i) {
                int node = blockBase + rt * 16 + q * 4 + i;
                if (node < N) G0[(size_t)node * 128 + col] = (_Float16)acc[i];
            }
        }
    }
}

// ---------------- fused agg (+ optional next-layer GEMM) ----------------

#define FMA8(hv, wv_)                                                                        \
    {                                                                                        \
        float2 f;                                                                            \
        f = __half22float2(*(const __half2*)&(hv).x); acc[0] += f.x * (wv_); acc[1] += f.y * (wv_); \
        f = __half22float2(*(const __half2*)&(hv).y); acc[2] += f.x * (wv_); acc[3] += f.y * (wv_); \
        f = __half22float2(*(const __half2*)&(hv).z); acc[4] += f.x * (wv_); acc[5] += f.y * (wv_); \
        f = __half22float2(*(const __half2*)&(hv).w); acc[6] += f.x * (wv_); acc[7] += f.y * (wv_); \
    }

template <int MODE>   // 1: fused GEMM out fp16; 0: final fp32 out
__global__ __launch_bounds__(256) void k_agg_gemm(const uint4* __restrict__ H4, const int* __restrict__ offs,
                                                  const int2* __restrict__ cpack,
                                                  const float* __restrict__ bias,
                                                  const _Float16* __restrict__ WTnext,
                                                  void* __restrict__ Yv, int N) {
    __shared__ _Float16 Zl[16][136];

    int t = threadIdx.x;
    int grp = t >> 4;                 // 0..15: node slot in block
    int li = t & 15;                  // lane in group: cols li*8..+7
    int blockBase = blockIdx.x * 16;
    int node = blockBase + grp;

    float acc[8];
    #pragma unroll
    for (int k = 0; k < 8; ++k) acc[k] = 0.f;

    if (node < N) {
        int i0 = offs[node], i1 = offs[node + 1];
        for (int base = i0; base < i1; base += 16) {
            int navail = i1 - base; if (navail > 16) navail = 16;
            int lidx = li < navail ? li : (navail - 1);
            int2 ep = cpack[base + lidx];

            float wA[4]; uint4 hA[4];
            #pragma unroll
            for (int j = 0; j < 4; ++j) {
                int cl = j < navail ? j : (navail - 1);
                int s = __shfl(ep.x, cl, 16);
                float wj = __int_as_float(__shfl(ep.y, cl, 16));
                wA[j] = j < navail ? wj : 0.f;
                hA[j] = H4[(size_t)s * 16 + li];
            }
            for (int e = 4; e < navail; e += 4) {
                float wB[4]; uint4 hB[4];
                #pragma unroll
                for (int j = 0; j < 4; ++j) {
                    int idx = e + j;
                    int cl = idx < navail ? idx : (navail - 1);
                    int s = __shfl(ep.x, cl, 16);
                    float wj = __int_as_float(__shfl(ep.y, cl, 16));
                    wB[j] = idx < navail ? wj : 0.f;
                    hB[j] = H4[(size_t)s * 16 + li];
                }
                #pragma unroll
                for (int j = 0; j < 4; ++j) FMA8(hA[j], wA[j]);
                #pragma unroll
                for (int j = 0; j < 4; ++j) { wA[j] = wB[j]; hA[j] = hB[j]; }
            }
            #pragma unroll
            for (int j = 0; j < 4; ++j) FMA8(hA[j], wA[j]);
        }
    }

    float4 b0 = *(const float4*)&bias[li * 8];
    float4 b1 = *(const float4*)&bias[li * 8 + 4];
    acc[0] += b0.x; acc[1] += b0.y; acc[2] += b0.z; acc[3] += b0.w;
    acc[4] += b1.x; acc[5] += b1.y; acc[6] += b1.z; acc[7] += b1.w;

    if (MODE == 0) {
        if (node < N) {
            float* Yf = (float*)Yv;
            *(float4*)&Yf[(size_t)node * 128 + li * 8]     = make_float4(acc[0], acc[1], acc[2], acc[3]);
            *(float4*)&Yf[(size_t)node * 128 + li * 8 + 4] = make_float4(acc[4], acc[5], acc[6], acc[7]);
        }
        return;
    }

    // MODE 1: F = relu(Z) -> LDS fp16, then G = F @ Wnext
    {
        h8 fr;
        #pragma unroll
        for (int k = 0; k < 8; ++k) fr[k] = (_Float16)fmaxf(acc[k], 0.f);
        *(h8*)&Zl[grp][li * 8] = fr;
    }
    __syncthreads();

    int wv = t >> 6, lane = t & 63;
    int r = lane & 15, q = lane >> 4;
    _Float16* G = (_Float16*)Yv;
    h8 a[4];
    #pragma unroll
    for (int s = 0; s < 4; ++s) a[s] = *(const h8*)&Zl[r][s * 32 + q * 8];
    #pragma unroll
    for (int ct2 = 0; ct2 < 2; ++ct2) {
        int col = (wv * 2 + ct2) * 16 + r;
        f4 gacc = {0.f, 0.f, 0.f, 0.f};
        #pragma unroll
        for (int s = 0; s < 4; ++s) {
            h8 bv = *(const h8*)&WTnext[(size_t)col * 128 + s * 32 + q * 8];
            gacc = __builtin_amdgcn_mfma_f32_16x16x32_f16(a[s], bv, gacc, 0, 0, 0);
        }
        #pragma unroll
        for (int i = 0; i < 4; ++i) {
            int nrow = blockBase + q * 4 + i;
            if (nrow < N) G[(size_t)nrow * 128 + col] = (_Float16)gacc[i];
        }
    }
}

// ---------------- launch ----------------

extern "C" void kernel_launch(void* const* d_in, const int* in_sizes, int n_in,
                              void* d_out, int out_size, void* d_ws, size_t ws_size,
                              hipStream_t stream) {
    const int*   label = (const int*)d_in[0];
    const float* bbox  = (const float*)d_in[1];
    const int*   eidx  = (const int*)d_in[2];
    const float* emb   = (const float*)d_in[3];
    const float* w1    = (const float*)d_in[4];
    const float* b1    = (const float*)d_in[5];
    const float* w2    = (const float*)d_in[6];
    const float* b2    = (const float*)d_in[7];
    const float* wg0   = (const float*)d_in[8];
    const float* bg0   = (const float*)d_in[9];
    const float* wg1   = (const float*)d_in[10];
    const float* bg1   = (const float*)d_in[11];
    const float* wg2   = (const float*)d_in[12];
    const float* bg2   = (const float*)d_in[13];

    int N = in_sizes[0];
    int E = in_sizes[2] / 2;
    const int* esrc = eidx;
    const int* edst = eidx + E;

    char* ws = (char*)d_ws;
    int*       offs     = (int*)      (ws + 0x000000);   // N+1 ints
    float*     dinv     = (float*)    (ws + 0x070000);   // N floats
    int*       partials = (int*)      (ws + 0x150000);   // <=512 ints
    _Float16*  WT       = (_Float16*) (ws + 0x160000);   // 3*128*128 + 64*64 halves (~104KB)
    long long* cpack    = (long long*)(ws + 0x200000);   // (E+N) int2 (~13.6MB)
    __half*    B        = (__half*)   (ws + 0x1000000);  // N*128 halves
    int*       cnt_pad  = (int*)      (ws + 0x1000000);  // aliases B (dead before first agg)
    int*       rank     = (int*)      (ws + 0x1800000);  // aliases B tail (dead before first agg)
    __half*    A        = (__half*)   (ws + 0x2900000);  // N*128 halves
    float*     Of       = (float*)    d_out;

    _Float16* W2Th = WT + 3 * 16384;

    int nb = (N + 255) / 256;
    int ebCount = (E + 255) / 256;
    int featBlocks = (N + 31) / 32;

    hipMemsetAsync(cnt_pad, 0, (size_t)N * CNT_PAD * 4, stream);
    k_prep_w<<<192, 256, 0, stream>>>(wg0, wg1, wg2, WT);
    k_prep_w2<<<16, 256, 0, stream>>>(w2, W2Th);

    // merged: edge-count blocks + feat/GEMM0 blocks in one dispatch (independent work)
    k_count_feat<<<ebCount + featBlocks, 256, 0, stream>>>(
        edst, cnt_pad, rank, E, ebCount,
        label, bbox, emb, w1, b1, b2, W2Th, WT + 0 * 16384, (_Float16*)A, N);

    k_scan_a<<<nb, 256, 0, stream>>>(cnt_pad, offs, partials, dinv, N);
    k_scan_b<<<1, 512, 0, stream>>>(partials, nb);
    k_scan_c<<<(N + 1 + 255) / 256, 256, 0, stream>>>(offs, partials, cnt_pad, dinv, cpack, N, nb);
    k_fill2<<<ebCount, 256, 0, stream>>>(esrc, edst, rank, offs, dinv, cpack, E);

    int agg_grid = (N + 15) / 16;

    // G1 = relu(A_hat G0 + b0) @ W1 -> B
    k_agg_gemm<1><<<agg_grid, 256, 0, stream>>>((const uint4*)A, offs, (const int2*)cpack, bg0,
                                                WT + 1 * 16384, B, N);
    // G2 = relu(A_hat G1 + b1) @ W2 -> A
    k_agg_gemm<1><<<agg_grid, 256, 0, stream>>>((const uint4*)B, offs, (const int2*)cpack, bg1,
                                                WT + 2 * 16384, A, N);
    // OUT = A_hat G2 + b2  (fp32)
    k_agg_gemm<0><<<agg_grid, 256, 0, stream>>>((const uint4*)A, offs, (const int2*)cpack, bg2,
                                                nullptr, Of, N);
}

// Round 19
// 358.779 us; speedup vs baseline: 1.0420x; 1.0420x over previous
//
#include <hip/hip_runtime.h>
#include <hip/hip_bf16.h>
#include <hip/hip_fp16.h>
#include <cstdint>
#include <cstddef>

typedef _Float16 h8 __attribute__((ext_vector_type(8)));
typedef float f4 __attribute__((ext_vector_type(4)));

#define CNT_PAD 16   // one counter per 64B line

// ---------------- CSR scans ----------------

__global__ __launch_bounds__(256) void k_scan_a(const int* __restrict__ cnt_pad, int* __restrict__ offs,
                                                int* __restrict__ partials, float* __restrict__ dinv, int N) {
    __shared__ int sh[256];
    int t = threadIdx.x;
    int i = blockIdx.x * 256 + t;
    int v = (i < N) ? (cnt_pad[(size_t)i * CNT_PAD] + 1) : 0;
    sh[t] = v;
    __syncthreads();
    for (int d = 1; d < 256; d <<= 1) {
        int add = (t >= d) ? sh[t - d] : 0;
        __syncthreads();
        sh[t] += add;
        __syncthreads();
    }
    if (i < N) {
        offs[i] = sh[t] - v;
        dinv[i] = rsqrtf((float)v);
    }
    if (t == 255) partials[blockIdx.x] = sh[255];
}

__global__ __launch_bounds__(512) void k_scan_b(int* __restrict__ partials, int nb) {
    __shared__ int sh[512];
    int t = threadIdx.x;
    int v = (t < nb) ? partials[t] : 0;
    sh[t] = v;
    __syncthreads();
    for (int d = 1; d < 512; d <<= 1) {
        int add = (t >= d) ? sh[t - d] : 0;
        __syncthreads();
        sh[t] += add;
        __syncthreads();
    }
    if (t < nb) partials[t] = sh[t];
}

// finalize offs; pack ninfo=(offs,dinv); write self-loop record at offs[i]+cnt
__global__ __launch_bounds__(256) void k_scan_c(int* __restrict__ offs, const int* __restrict__ partials,
                                                const int* __restrict__ cnt_pad, const float* __restrict__ dinv,
                                                long long* __restrict__ cpack, int2* __restrict__ ninfo,
                                                int N, int nb) {
    int i = blockIdx.x * 256 + threadIdx.x;
    if (i < N) {
        int b = i >> 8;
        int o = offs[i] + (b > 0 ? partials[b - 1] : 0);
        offs[i] = o;
        int cnt = cnt_pad[(size_t)i * CNT_PAD];
        float di = dinv[i];
        ninfo[i] = make_int2(o, __float_as_int(di));
        unsigned int nrm = (unsigned int)__float_as_int(di * di);
        long long v = ((long long)nrm << 32) | (unsigned int)i;
        __builtin_nontemporal_store(v, &cpack[o + cnt]);
    } else if (i == N) {
        offs[N] = partials[nb - 1];
    }
}

// no atomic: pos = ninfo[d].x + rank; one random 8B read per edge; NT scatter
__global__ __launch_bounds__(256) void k_fill2(const int* __restrict__ src, const int* __restrict__ dst,
                                               const int* __restrict__ rank, const int2* __restrict__ ninfo,
                                               const float* __restrict__ dinv,
                                               long long* __restrict__ cpack, int E) {
    int i = blockIdx.x * 256 + threadIdx.x;
    if (i < E) {
        int s = src[i], d = dst[i];
        int2 nd = ninfo[d];
        int pos = nd.x + rank[i];
        unsigned int nrm = (unsigned int)__float_as_int(dinv[s] * __int_as_float(nd.y));
        long long v = ((long long)nrm << 32) | (unsigned int)s;
        __builtin_nontemporal_store(v, &cpack[pos]);
    }
}

// ---------------- weight prep (once) ----------------
// WT[l][c][k] = W_l[k][c] fp16 (3x128x128); W2T[c][k] = w2[k][c] fp16 (64x64)

__global__ __launch_bounds__(256) void k_prep_w(const float* __restrict__ w0, const float* __restrict__ w1,
                                                const float* __restrict__ w2g, _Float16* __restrict__ WT) {
    int idx = blockIdx.x * 256 + threadIdx.x;
    if (idx < 3 * 16384) {
        int l = idx >> 14, rem = idx & 16383, c = rem >> 7, k = rem & 127;
        const float* W = (l == 0) ? w0 : (l == 1) ? w1 : w2g;
        WT[idx] = (_Float16)W[k * 128 + c];
    }
}

__global__ __launch_bounds__(256) void k_prep_w2(const float* __restrict__ w2, _Float16* __restrict__ W2T) {
    int idx = blockIdx.x * 256 + threadIdx.x;   // 4096 elems
    if (idx < 4096) {
        int c = idx >> 6, k = idx & 63;
        W2T[idx] = (_Float16)w2[k * 64 + c];
    }
}

// ---------------- merged: edge count+rank ∥ feat+GEMM0, INTERLEAVED roles ----------------
// role = blockIdx%3: {0,1} -> count (2 sub-blocks per g), {2} -> feat.
// Every CU holds both atomic-latency-bound count waves and MFMA feat waves
// throughout the dispatch (round-18's range split only overlapped at the tail).

__global__ __launch_bounds__(256) void k_count_feat(const int* __restrict__ edst, int* __restrict__ cnt_pad,
                                                    int* __restrict__ rank, int E, int ebCount,
                                                    const int* __restrict__ label, const float* __restrict__ bbox,
                                                    const float* __restrict__ emb,
                                                    const float* __restrict__ w1, const float* __restrict__ b1,
                                                    const float* __restrict__ b2,
                                                    const _Float16* __restrict__ W2Th,
                                                    const _Float16* __restrict__ WT0,
                                                    _Float16* __restrict__ G0, int N) {
    int t = threadIdx.x;
    int g = blockIdx.x / 3, role = blockIdx.x % 3;

    if (role < 2) {
        // ---- edge count + rank capture (no LDS touched) ----
        int cb = g * 2 + role;
        if (cb < ebCount) {
            int i = cb * 256 + t;
            if (i < E) rank[i] = atomicAdd(&cnt_pad[(size_t)edst[i] * CNT_PAD], 1);
        }
        return;
    }

    // ---- feat + GEMM0 (block g handles nodes [g*32, g*32+32)) ----
    int blockBase = g * 32;
    if (blockBase >= N) return;

    __shared__ float w1s[256];
    __shared__ float b1s[64], b2s[64];
    __shared__ _Float16 Fl[32][136];

    if (t < 256) w1s[t] = w1[t];
    if (t < 64) { b1s[t] = b1[t]; b2s[t] = b2[t]; }
    __syncthreads();   // w1s/b1s written by other waves — barrier before use

    int wv = t >> 6, lane = t & 63;
    int r = lane & 15, q = lane >> 4;
    int nb0 = blockBase + wv * 8;

    // phase 1: ev -> Fl cols 0..63; h1 fp16 -> Fl cols 64..127
    #pragma unroll
    for (int nn = 0; nn < 8; ++nn) {
        int node = nb0 + nn;
        float h1 = 0.f;
        _Float16 ev = (_Float16)0.f;
        if (node < N) {
            float bb0 = bbox[node * 4 + 0];
            float bb1 = bbox[node * 4 + 1];
            float bb2 = bbox[node * 4 + 2];
            float bb3 = bbox[node * 4 + 3];
            h1 = fmaxf(bb0 * w1s[lane] + bb1 * w1s[64 + lane]
                     + bb2 * w1s[128 + lane] + bb3 * w1s[192 + lane] + b1s[lane], 0.f);
            ev = (_Float16)emb[(size_t)label[node] * 64 + lane];
        }
        Fl[wv * 8 + nn][lane] = ev;
        Fl[wv * 8 + nn][64 + lane] = (_Float16)h1;
    }
    __syncthreads();

    int rt = wv & 1, ch = wv >> 1;

    // phase 2a: read h1 A-frags, barrier, then overwrite cols 64..127 with h2
    h8 a0 = *(const h8*)&Fl[rt * 16 + r][64 + q * 8];
    h8 a1 = *(const h8*)&Fl[rt * 16 + r][96 + q * 8];
    __syncthreads();   // all h1 reads complete before any h2 write
    #pragma unroll
    for (int ct = 0; ct < 2; ++ct) {
        int col = ch * 32 + ct * 16 + r;
        h8 bv0 = *(const h8*)&W2Th[col * 64 + q * 8];
        h8 bv1 = *(const h8*)&W2Th[col * 64 + 32 + q * 8];
        f4 acc = {0.f, 0.f, 0.f, 0.f};
        acc = __builtin_amdgcn_mfma_f32_16x16x32_f16(a0, bv0, acc, 0, 0, 0);
        acc = __builtin_amdgcn_mfma_f32_16x16x32_f16(a1, bv1, acc, 0, 0, 0);
        float bb = b2s[col];
        #pragma unroll
        for (int i = 0; i < 4; ++i)
            Fl[rt * 16 + q * 4 + i][64 + col] = (_Float16)(acc[i] + bb);
    }
    __syncthreads();

    // phase 2b: G0 = Fl @ W0 (K=128)
    {
        h8 a[4];
        #pragma unroll
        for (int s = 0; s < 4; ++s) a[s] = *(const h8*)&Fl[rt * 16 + r][s * 32 + q * 8];
        #pragma unroll
        for (int ct = 0; ct < 4; ++ct) {
            int col = ch * 64 + ct * 16 + r;
            f4 acc = {0.f, 0.f, 0.f, 0.f};
            #pragma unroll
            for (int s = 0; s < 4; ++s) {
                h8 bv = *(const h8*)&WT0[(size_t)col * 128 + s * 32 + q * 8];
                acc = __builtin_amdgcn_mfma_f32_16x16x32_f16(a[s], bv, acc, 0, 0, 0);
            }
            #pragma unroll
            for (int i = 0; i < 4; ++i) {
                int node = blockBase + rt * 16 + q * 4 + i;
                if (node < N) G0[(size_t)node * 128 + col] = (_Float16)acc[i];
            }
        }
    }
}

// ---------------- fused agg (+ optional next-layer GEMM) ----------------

#define FMA8(hv, wv_)                                                                        \
    {                                                                                        \
        float2 f;                                                                            \
        f = __half22float2(*(const __half2*)&(hv).x); acc[0] += f.x * (wv_); acc[1] += f.y * (wv_); \
        f = __half22float2(*(const __half2*)&(hv).y); acc[2] += f.x * (wv_); acc[3] += f.y * (wv_); \
        f = __half22float2(*(const __half2*)&(hv).z); acc[4] += f.x * (wv_); acc[5] += f.y * (wv_); \
        f = __half22float2(*(const __half2*)&(hv).w); acc[6] += f.x * (wv_); acc[7] += f.y * (wv_); \
    }

template <int MODE>   // 1: fused GEMM out fp16; 0: final fp32 out
__global__ __launch_bounds__(256) void k_agg_gemm(const uint4* __restrict__ H4, const int* __restrict__ offs,
                                                  const int2* __restrict__ cpack,
                                                  const float* __restrict__ bias,
                                                  const _Float16* __restrict__ WTnext,
                                                  void* __restrict__ Yv, int N) {
    __shared__ _Float16 Zl[16][136];

    int t = threadIdx.x;
    int grp = t >> 4;                 // 0..15: node slot in block
    int li = t & 15;                  // lane in group: cols li*8..+7
    int blockBase = blockIdx.x * 16;
    int node = blockBase + grp;

    float acc[8];
    #pragma unroll
    for (int k = 0; k < 8; ++k) acc[k] = 0.f;

    if (node < N) {
        int i0 = offs[node], i1 = offs[node + 1];
        for (int base = i0; base < i1; base += 16) {
            int navail = i1 - base; if (navail > 16) navail = 16;
            int lidx = li < navail ? li : (navail - 1);
            int2 ep = cpack[base + lidx];

            float wA[4]; uint4 hA[4];
            #pragma unroll
            for (int j = 0; j < 4; ++j) {
                int cl = j < navail ? j : (navail - 1);
                int s = __shfl(ep.x, cl, 16);
                float wj = __int_as_float(__shfl(ep.y, cl, 16));
                wA[j] = j < navail ? wj : 0.f;
                hA[j] = H4[(size_t)s * 16 + li];
            }
            for (int e = 4; e < navail; e += 4) {
                float wB[4]; uint4 hB[4];
                #pragma unroll
                for (int j = 0; j < 4; ++j) {
                    int idx = e + j;
                    int cl = idx < navail ? idx : (navail - 1);
                    int s = __shfl(ep.x, cl, 16);
                    float wj = __int_as_float(__shfl(ep.y, cl, 16));
                    wB[j] = idx < navail ? wj : 0.f;
                    hB[j] = H4[(size_t)s * 16 + li];
                }
                #pragma unroll
                for (int j = 0; j < 4; ++j) FMA8(hA[j], wA[j]);
                #pragma unroll
                for (int j = 0; j < 4; ++j) { wA[j] = wB[j]; hA[j] = hB[j]; }
            }
            #pragma unroll
            for (int j = 0; j < 4; ++j) FMA8(hA[j], wA[j]);
        }
    }

    float4 b0 = *(const float4*)&bias[li * 8];
    float4 b1 = *(const float4*)&bias[li * 8 + 4];
    acc[0] += b0.x; acc[1] += b0.y; acc[2] += b0.z; acc[3] += b0.w;
    acc[4] += b1.x; acc[5] += b1.y; acc[6] += b1.z; acc[7] += b1.w;

    if (MODE == 0) {
        if (node < N) {
            float* Yf = (float*)Yv;
            *(float4*)&Yf[(size_t)node * 128 + li * 8]     = make_float4(acc[0], acc[1], acc[2], acc[3]);
            *(float4*)&Yf[(size_t)node * 128 + li * 8 + 4] = make_float4(acc[4], acc[5], acc[6], acc[7]);
        }
        return;
    }

    // MODE 1: F = relu(Z) -> LDS fp16, then G = F @ Wnext
    {
        h8 fr;
        #pragma unroll
        for (int k = 0; k < 8; ++k) fr[k] = (_Float16)fmaxf(acc[k], 0.f);
        *(h8*)&Zl[grp][li * 8] = fr;
    }
    __syncthreads();

    int wv = t >> 6, lane = t & 63;
    int r = lane & 15, q = lane >> 4;
    _Float16* G = (_Float16*)Yv;
    h8 a[4];
    #pragma unroll
    for (int s = 0; s < 4; ++s) a[s] = *(const h8*)&Zl[r][s * 32 + q * 8];
    #pragma unroll
    for (int ct2 = 0; ct2 < 2; ++ct2) {
        int col = (wv * 2 + ct2) * 16 + r;
        f4 gacc = {0.f, 0.f, 0.f, 0.f};
        #pragma unroll
        for (int s = 0; s < 4; ++s) {
            h8 bv = *(const h8*)&WTnext[(size_t)col * 128 + s * 32 + q * 8];
            gacc = __builtin_amdgcn_mfma_f32_16x16x32_f16(a[s], bv, gacc, 0, 0, 0);
        }
        #pragma unroll
        for (int i = 0; i < 4; ++i) {
            int nrow = blockBase + q * 4 + i;
            if (nrow < N) G[(size_t)nrow * 128 + col] = (_Float16)gacc[i];
        }
    }
}

// ---------------- launch ----------------

extern "C" void kernel_launch(void* const* d_in, const int* in_sizes, int n_in,
                              void* d_out, int out_size, void* d_ws, size_t ws_size,
                              hipStream_t stream) {
    const int*   label = (const int*)d_in[0];
    const float* bbox  = (const float*)d_in[1];
    const int*   eidx  = (const int*)d_in[2];
    const float* emb   = (const float*)d_in[3];
    const float* w1    = (const float*)d_in[4];
    const float* b1    = (const float*)d_in[5];
    const float* w2    = (const float*)d_in[6];
    const float* b2    = (const float*)d_in[7];
    const float* wg0   = (const float*)d_in[8];
    const float* bg0   = (const float*)d_in[9];
    const float* wg1   = (const float*)d_in[10];
    const float* bg1   = (const float*)d_in[11];
    const float* wg2   = (const float*)d_in[12];
    const float* bg2   = (const float*)d_in[13];

    int N = in_sizes[0];
    int E = in_sizes[2] / 2;
    const int* esrc = eidx;
    const int* edst = eidx + E;

    char* ws = (char*)d_ws;
    int*       offs     = (int*)      (ws + 0x000000);   // N+1 ints
    float*     dinv     = (float*)    (ws + 0x070000);   // N floats
    int*       partials = (int*)      (ws + 0x150000);   // <=512 ints
    _Float16*  WT       = (_Float16*) (ws + 0x160000);   // 3*128*128 + 64*64 halves (~104KB)
    int2*      ninfo    = (int2*)     (ws + 0x180000);   // N int2 (800KB)
    long long* cpack    = (long long*)(ws + 0x280000);   // (E+N) int2 (~13.6MB) -> ends ~0xF80000
    __half*    B        = (__half*)   (ws + 0x1000000);  // N*128 halves
    int*       cnt_pad  = (int*)      (ws + 0x1000000);  // aliases B (dead before first agg)
    int*       rank     = (int*)      (ws + 0x1800000);  // aliases B tail (dead before first agg)
    __half*    A        = (__half*)   (ws + 0x2900000);  // N*128 halves
    float*     Of       = (float*)    d_out;

    _Float16* W2Th = WT + 3 * 16384;

    int nb = (N + 255) / 256;
    int ebCount = (E + 255) / 256;
    int featBlocks = (N + 31) / 32;
    int gmax = (ebCount + 1) / 2;
    if (featBlocks > gmax) gmax = featBlocks;

    hipMemsetAsync(cnt_pad, 0, (size_t)N * CNT_PAD * 4, stream);
    k_prep_w<<<192, 256, 0, stream>>>(wg0, wg1, wg2, WT);
    k_prep_w2<<<16, 256, 0, stream>>>(w2, W2Th);

    // merged + interleaved: count and feat blocks round-robin on every CU
    k_count_feat<<<3 * gmax, 256, 0, stream>>>(
        edst, cnt_pad, rank, E, ebCount,
        label, bbox, emb, w1, b1, b2, W2Th, WT + 0 * 16384, (_Float16*)A, N);

    k_scan_a<<<nb, 256, 0, stream>>>(cnt_pad, offs, partials, dinv, N);
    k_scan_b<<<1, 512, 0, stream>>>(partials, nb);
    k_scan_c<<<(N + 1 + 255) / 256, 256, 0, stream>>>(offs, partials, cnt_pad, dinv, cpack, ninfo, N, nb);
    k_fill2<<<ebCount, 256, 0, stream>>>(esrc, edst, rank, ninfo, dinv, cpack, E);

    int agg_grid = (N + 15) / 16;

    // G1 = relu(A_hat G0 + b0) @ W1 -> B
    k_agg_gemm<1><<<agg_grid, 256, 0, stream>>>((const uint4*)A, offs, (const int2*)cpack, bg0,
                                                WT + 1 * 16384, B, N);
    // G2 = relu(A_hat G1 + b1) @ W2 -> A
    k_agg_gemm<1><<<agg_grid, 256, 0, stream>>>((const uint4*)B, offs, (const int2*)cpack, bg1,
                                                WT + 2 * 16384, A, N);
    // OUT = A_hat G2 + b2  (fp32)
    k_agg_gemm<0><<<agg_grid, 256, 0, stream>>>((const uint4*)A, offs, (const int2*)cpack, bg2,
                                                nullptr, Of, N);
}